// Round 4
// baseline (359.442 us; speedup 1.0000x reference)
//
#include <hip/hip_runtime.h>
#include <hip/hip_bf16.h>

#define HID 128
#define NRAD 16

typedef __attribute__((ext_vector_type(4))) float f32x4;
typedef __attribute__((ext_vector_type(8))) __bf16 bf16x8;
typedef __attribute__((ext_vector_type(4))) __bf16 bf16x4;

union F8 { bf16x8 b; int4 i4; };
union B4 { bf16x4 b4; int2 i2; };

__device__ inline unsigned short f2bfbits(float f){
  unsigned int u = __float_as_uint(f);
  u += 0x7FFFu + ((u >> 16) & 1u);   // round-to-nearest-even
  return (unsigned short)(u >> 16);
}

__device__ inline float silu_f(float v){
  return v * __builtin_amdgcn_rcpf(1.0f + __expf(-v));
}

// ---------------------------------------------------------------------------
// Fused setup (one launch):
//   blocks [0, ntypes)            : P[t][0:128]=emb@W1^T+b_lin ; P[t][128:256]=emb@W2^T
//   blocks [ntypes, ntypes+64)    : W3 bf16 conversion  (128x128)
//   blocks [ntypes+64, ntypes+72) : W_rbf bf16 conversion (128x16)
// ---------------------------------------------------------------------------
__global__ void setup_kernel(const float* __restrict__ emb,
                             const float* __restrict__ W_lin,
                             const float* __restrict__ b_lin,
                             const float* __restrict__ W_rbf,
                             int ntypes,
                             float* __restrict__ P,
                             unsigned short* __restrict__ W3,
                             unsigned short* __restrict__ WrbfB){
  int blk = blockIdx.x;
  int n = threadIdx.x;                // 0..255
  if (blk < ntypes){
    __shared__ float er[HID];
    if (n < HID) er[n] = emb[blk * HID + n];
    __syncthreads();
    int half = n >> 7, nn = n & 127;
    const float4* w4 = (const float4*)(W_lin + (size_t)nn * (3 * HID) + half * HID);
    float s = half ? 0.0f : b_lin[nn];
    #pragma unroll 8
    for (int k4 = 0; k4 < HID / 4; ++k4){
      float4 w = w4[k4];
      s += er[k4*4+0]*w.x + er[k4*4+1]*w.y + er[k4*4+2]*w.z + er[k4*4+3]*w.w;
    }
    P[blk * 256 + n] = s;
  } else if (blk < ntypes + 64){
    int idx = (blk - ntypes) * 256 + n;       // 0..16383
    int r = idx >> 7, k = idx & 127;
    W3[idx] = f2bfbits(W_lin[(size_t)r * (3 * HID) + 2 * HID + k]);
  } else {
    int idx = (blk - ntypes - 64) * 256 + n;  // 0..2047 ; W_rbf is [128][16] row-major
    WrbfB[idx] = f2bfbits(W_rbf[idx]);
  }
}

// ---------------------------------------------------------------------------
// Fused edge kernel, grid-stride over 64-edge tiles, software-pipelined.
// 4 waves/block, each wave fully owns 16 edges (no __syncthreads at all:
// each wave writes and reads only rb rows [wv*16, wv*16+16)).
// D-orientation [n][edge]: each lane owns ONE edge and 4 consecutive n.
//   phase 1: r = silu(rbf @ Wrbf^T + brbf)  -> bf16, XOR-swizzled LDS
//   phase 2: acc = W3 * r^T                 (4 K-steps x 8 N-tiles of MFMA)
//   epilogue: out = silu(acc + P1[x[i]] + P2[x[j]])
// Pipeline: next tile's rbf/ei/ej are loaded during the current tile's
// compute; x[ei] gathers issue at loop top so P-gather latency is hidden.
// ---------------------------------------------------------------------------
__global__ __launch_bounds__(256) void edge_kernel(
    const float* __restrict__ rbf,
    const int*   __restrict__ ei,
    const int*   __restrict__ ej,
    const int*   __restrict__ x,
    const unsigned short* __restrict__ WrbfB, // bf16 bits, [128][16]
    const float* __restrict__ brbf,
    const float* __restrict__ P,
    const unsigned short* __restrict__ W3,    // bf16 bits, [128][128]
    float* __restrict__ out,
    int E)
{
  const int tid  = threadIdx.x;
  const int lane = tid & 63;
  const int wv   = tid >> 6;        // wave 0..3
  const int erow = lane & 15;       // this lane's edge-within-wave AND W row idx
  const int kgrp = lane >> 4;       // 0..3 (K-group / D row group)
  const int e_l  = wv * 16 + erow;  // local edge this lane owns (B col / D col)

  __shared__ char rb[64 * 256];     // 16 KB swizzled bf16 r-tile [64 edges][128 n]

  const int ntile = (E + 63) >> 6;
  int tile = blockIdx.x;

  // ---- prefetch for first tile --------------------------------------------
  int eic = 0, ejc = 0;
  f32x4 f0 = {0.f,0.f,0.f,0.f}, f1 = {0.f,0.f,0.f,0.f};
  if (tile < ntile){
    long ge = (long)tile * 64 + e_l;
    if (ge < E){
      eic = ei[ge]; ejc = ej[ge];
      if (kgrp < 2){
        const f32x4* s4 = (const f32x4*)(rbf + ge * NRAD + kgrp * 8);
        f0 = __builtin_nontemporal_load(s4);
        f1 = __builtin_nontemporal_load(s4 + 1);
      }
    }
  }

  while (tile < ntile){
    const long ge   = (long)tile * 64 + e_l;
    const int  next = tile + gridDim.x;

    // dependent gather chain for CURRENT tile — issue ASAP
    int a = x[eic];
    int b = x[ejc];

    // build B fragment (rbf cols = edges) from prefetched registers
    F8 fbB; fbB.i4 = make_int4(0, 0, 0, 0);
    if (kgrp < 2){
      fbB.b[0]=(__bf16)f0.x; fbB.b[1]=(__bf16)f0.y; fbB.b[2]=(__bf16)f0.z; fbB.b[3]=(__bf16)f0.w;
      fbB.b[4]=(__bf16)f1.x; fbB.b[5]=(__bf16)f1.y; fbB.b[6]=(__bf16)f1.z; fbB.b[7]=(__bf16)f1.w;
    }

    // ---- prefetch NEXT tile (hidden under this tile's compute) ------------
    int ein = 0, ejn = 0;
    f32x4 nf0 = {0.f,0.f,0.f,0.f}, nf1 = {0.f,0.f,0.f,0.f};
    if (next < ntile){
      long gn = (long)next * 64 + e_l;
      if (gn < E){
        ein = ei[gn]; ejn = ej[gn];
        if (kgrp < 2){
          const f32x4* s4 = (const f32x4*)(rbf + gn * NRAD + kgrp * 8);
          nf0 = __builtin_nontemporal_load(s4);
          nf1 = __builtin_nontemporal_load(s4 + 1);
        }
      }
    }

    // ---- phase 1: r tile (wave-local) -------------------------------------
    #pragma unroll
    for (int t = 0; t < 8; ++t){
      F8 fa; fa.i4 = make_int4(0, 0, 0, 0);
      if (kgrp < 2) fa.i4 = *(const int4*)(WrbfB + (t * 16 + erow) * NRAD + kgrp * 8);
      f32x4 acc = {0.f, 0.f, 0.f, 0.f};
      acc = __builtin_amdgcn_mfma_f32_16x16x32_bf16(fa.b, fbB.b, acc, 0, 0, 0);
      // D: col = erow (edge e_l), row = kgrp*4+r  -> n = t*16 + kgrp*4 + r
      float4 bias4 = *(const float4*)(brbf + t * 16 + kgrp * 4);
      B4 pk;
      pk.b4[0] = (__bf16)silu_f(acc[0] + bias4.x);
      pk.b4[1] = (__bf16)silu_f(acc[1] + bias4.y);
      pk.b4[2] = (__bf16)silu_f(acc[2] + bias4.z);
      pk.b4[3] = (__bf16)silu_f(acc[3] + bias4.w);
      int byte = (e_l << 8) + t * 32 + kgrp * 8;
      byte ^= (e_l & 7) << 4;
      *(int2*)(rb + byte) = pk.i2;
    }

    // wave-local LDS RAW: make sure writes landed before reads (no barrier
    // needed — rows are wave-exclusive)
    asm volatile("s_waitcnt lgkmcnt(0)" ::: "memory");

    // ---- phase 2: acc = W3 * r^T ------------------------------------------
    f32x4 acc2[8];
    #pragma unroll
    for (int t = 0; t < 8; ++t) acc2[t] = (f32x4){0.f, 0.f, 0.f, 0.f};

    #pragma unroll
    for (int s = 0; s < 4; ++s){
      int byte = (e_l << 8) + s * 64 + kgrp * 16;
      byte ^= (e_l & 7) << 4;
      F8 bB; bB.i4 = *(const int4*)(rb + byte);   // B: col = edge e_l, k = s*32+kgrp*8
      #pragma unroll
      for (int t = 0; t < 8; ++t){
        F8 aW; aW.i4 = *(const int4*)(W3 + (t * 16 + erow) * HID + s * 32 + kgrp * 8);
        acc2[t] = __builtin_amdgcn_mfma_f32_16x16x32_bf16(aW.b, bB.b, acc2[t], 0, 0, 0);
      }
    }

    // ---- epilogue: lane owns edge ge, n = t*16 + kgrp*4 + (0..3) ----------
    const float4* p1 = (const float4*)(P + a * 256);
    const float4* p2 = (const float4*)(P + b * 256 + 128);
    #pragma unroll
    for (int t = 0; t < 8; ++t){
      int nq = t * 4 + kgrp;                      // float4 index of n = t*16+kgrp*4
      float4 v1 = p1[nq];
      float4 v2 = p2[nq];
      f32x4 o;
      o.x = silu_f(acc2[t][0] + v1.x + v2.x);
      o.y = silu_f(acc2[t][1] + v1.y + v2.y);
      o.z = silu_f(acc2[t][2] + v1.z + v2.z);
      o.w = silu_f(acc2[t][3] + v1.w + v2.w);
      if (ge < E)
        *(f32x4*)(out + ge * HID + t * 16 + kgrp * 4) = o;
    }

    // ---- rotate pipeline ---------------------------------------------------
    eic = ein; ejc = ejn; f0 = nf0; f1 = nf1;
    tile = next;
  }
}

// ---------------------------------------------------------------------------
extern "C" void kernel_launch(void* const* d_in, const int* in_sizes, int n_in,
                              void* d_out, int out_size, void* d_ws, size_t ws_size,
                              hipStream_t stream){
  const int*   x    = (const int*)  d_in[0];
  const float* rbf  = (const float*)d_in[1];
  const int*   ei   = (const int*)  d_in[2];
  const int*   ej   = (const int*)  d_in[3];
  const float* emb  = (const float*)d_in[4];
  const float* Wrbf = (const float*)d_in[5];
  const float* brbf = (const float*)d_in[6];
  const float* Wlin = (const float*)d_in[7];
  const float* blin = (const float*)d_in[8];
  float* out = (float*)d_out;

  const int E      = in_sizes[2];
  const int ntypes = in_sizes[4] / HID;   // 100

  float*          P     = (float*)d_ws;
  unsigned short* W3    = (unsigned short*)((char*)d_ws + (size_t)ntypes * 256 * sizeof(float));
  unsigned short* WrbfB = (unsigned short*)((char*)W3 + (size_t)HID * HID * sizeof(unsigned short));

  setup_kernel<<<ntypes + 64 + 8, 256, 0, stream>>>(emb, Wlin, blin, Wrbf, ntypes, P, W3, WrbfB);

  const int ntile = (E + 63) / 64;
  const int nblk  = ntile < 1536 ? ntile : 1536;
  edge_kernel<<<nblk, 256, 0, stream>>>(rbf, ei, ej, x, WrbfB, brbf, P, W3, out, E);
}

// Round 5
// 133.479 us; speedup vs baseline: 2.6929x; 2.6929x over previous
//
#include <hip/hip_runtime.h>
#include <hip/hip_bf16.h>

#define HID  128
#define NRAD 16
#define NT   100      // atom types (emb rows)

// LDS layout (dynamic):
//   Pl : [NT][260] f32 (padded rows -> 4-bank rotate)   104000 B
//   rb : [128 edges][256 B] swizzled bf16 r-tile         32768 B
//   aL : [128] int                                         512 B
//   bL : [128] int                                         512 B
#define PL_BYTES   (NT * 260 * 4)
#define RB_OFF     PL_BYTES
#define AL_OFF     (RB_OFF + 128 * 256)
#define BL_OFF     (AL_OFF + 512)
#define LDS_BYTES  (BL_OFF + 512)

typedef __attribute__((ext_vector_type(4))) float f32x4;
typedef __attribute__((ext_vector_type(8))) __bf16 bf16x8;
typedef __attribute__((ext_vector_type(4))) __bf16 bf16x4;

union F8 { bf16x8 b; int4 i4; };
union B4 { bf16x4 b4; int2 i2; };

__device__ inline unsigned short f2bfbits(float f){
  unsigned int u = __float_as_uint(f);
  u += 0x7FFFu + ((u >> 16) & 1u);
  return (unsigned short)(u >> 16);
}

__device__ inline float silu_f(float v){
  return v * __builtin_amdgcn_rcpf(1.0f + __expf(-v));
}

// ---------------------------------------------------------------------------
// Setup: P table, W3 bf16, Wrbf bf16 (one launch)
// ---------------------------------------------------------------------------
__global__ void setup_kernel(const float* __restrict__ emb,
                             const float* __restrict__ W_lin,
                             const float* __restrict__ b_lin,
                             const float* __restrict__ W_rbf,
                             int ntypes,
                             float* __restrict__ P,
                             unsigned short* __restrict__ W3,
                             unsigned short* __restrict__ WrbfB){
  int blk = blockIdx.x;
  int n = threadIdx.x;                // 0..255
  if (blk < ntypes){
    __shared__ float er[HID];
    if (n < HID) er[n] = emb[blk * HID + n];
    __syncthreads();
    int half = n >> 7, nn = n & 127;
    const float4* w4 = (const float4*)(W_lin + (size_t)nn * (3 * HID) + half * HID);
    float s = half ? 0.0f : b_lin[nn];
    #pragma unroll 8
    for (int k4 = 0; k4 < HID / 4; ++k4){
      float4 w = w4[k4];
      s += er[k4*4+0]*w.x + er[k4*4+1]*w.y + er[k4*4+2]*w.z + er[k4*4+3]*w.w;
    }
    P[blk * 256 + n] = s;
  } else if (blk < ntypes + 64){
    int idx = (blk - ntypes) * 256 + n;       // 0..16383
    int r = idx >> 7, k = idx & 127;
    W3[idx] = f2bfbits(W_lin[(size_t)r * (3 * HID) + 2 * HID + k]);
  } else {
    int idx = (blk - ntypes - 64) * 256 + n;  // 0..2047
    WrbfB[idx] = f2bfbits(W_rbf[idx]);
  }
}

// ---------------------------------------------------------------------------
// Edge kernel: 512 threads (8 waves), 128 edges/tile, grid-stride.
// Wave wv: phase1 computes r for edges [wv*16,wv*16+16); phase2 computes
// output n-slice [wv*16, wv*16+16) for ALL 128 edges (W3 slice in registers).
// P table lives in LDS; wave 0 handles the ei->x gather chain.
// ---------------------------------------------------------------------------
__global__ __launch_bounds__(512) void edge_kernel(
    const float* __restrict__ rbf,
    const int*   __restrict__ ei,
    const int*   __restrict__ ej,
    const int*   __restrict__ x,
    const unsigned short* __restrict__ WrbfB, // bf16 bits, [128][16]
    const float* __restrict__ brbf,
    const float* __restrict__ Pg,             // f32 [NT][256]
    const unsigned short* __restrict__ W3,    // bf16 bits, [128][128]
    float* __restrict__ out,
    int E, int ntile)
{
  extern __shared__ char smem[];
  float* Pl = (float*)smem;
  char*  rb = smem + RB_OFF;
  int*   aL = (int*)(smem + AL_OFF);
  int*   bL = (int*)(smem + BL_OFF);

  const int tid  = threadIdx.x;
  const int lane = tid & 63;
  const int wv   = tid >> 6;        // 0..7
  const int erow = lane & 15;
  const int kgrp = lane >> 4;       // 0..3

  // ---- stage P into LDS (rows padded to 260 floats) -----------------------
  for (int i = tid; i < NT * 64; i += 512){
    int row = i >> 6, c4 = i & 63;
    *(f32x4*)(Pl + row * 260 + c4 * 4) = *(const f32x4*)(Pg + row * 256 + c4 * 4);
  }

  // ---- loop-invariant register fragments ----------------------------------
  F8 wr[8];                                    // Wrbf rows, all 8 n-tiles
  #pragma unroll
  for (int t = 0; t < 8; ++t){
    wr[t].i4 = make_int4(0, 0, 0, 0);
    if (kgrp < 2) wr[t].i4 = *(const int4*)(WrbfB + (t * 16 + erow) * NRAD + kgrp * 8);
  }
  F8 w3[4];                                    // W3 rows for n-tile wv
  #pragma unroll
  for (int s = 0; s < 4; ++s)
    w3[s].i4 = *(const int4*)(W3 + (wv * 16 + erow) * HID + s * 32 + kgrp * 8);
  float4 bias[8];
  #pragma unroll
  for (int t = 0; t < 8; ++t) bias[t] = *(const float4*)(brbf + t * 16 + kgrp * 4);

  __syncthreads();                             // P staged

  // ---- pipeline prologue ---------------------------------------------------
  int tile = blockIdx.x;
  int2 e2 = make_int2(0, 0), j2 = make_int2(0, 0);
  if (tid < 64 && tile < ntile){
    long i0 = (long)tile * 128 + tid * 2;
    if (i0 > E - 2) i0 = E - 2;
    e2 = *(const int2*)(ei + i0);
    j2 = *(const int2*)(ej + i0);
  }
  f32x4 f0 = {0,0,0,0}, f1 = {0,0,0,0};
  if (tile < ntile && kgrp < 2){
    long ge = (long)tile * 128 + wv * 16 + erow;
    if (ge < E){
      const f32x4* s4 = (const f32x4*)(rbf + ge * NRAD + kgrp * 8);
      f0 = __builtin_nontemporal_load(s4);
      f1 = __builtin_nontemporal_load(s4 + 1);
    }
  }

  while (tile < ntile){
    const long base = (long)tile * 128;
    const int  next = tile + gridDim.x;

    // wave 0: x-gathers for CURRENT tile -> aL/bL, prefetch next ei/ej
    if (tid < 64){
      int2 av, bv;
      av.x = x[e2.x]; av.y = x[e2.y];
      bv.x = x[j2.x]; bv.y = x[j2.y];
      *(int2*)(aL + tid * 2) = av;
      *(int2*)(bL + tid * 2) = bv;
      if (next < ntile){
        long i0 = (long)next * 128 + tid * 2;
        if (i0 > E - 2) i0 = E - 2;
        e2 = *(const int2*)(ei + i0);
        j2 = *(const int2*)(ej + i0);
      }
    }

    // per-wave: prefetch next tile's rbf
    f32x4 nf0 = {0,0,0,0}, nf1 = {0,0,0,0};
    if (next < ntile && kgrp < 2){
      long gn = (long)next * 128 + wv * 16 + erow;
      if (gn < E){
        const f32x4* s4 = (const f32x4*)(rbf + gn * NRAD + kgrp * 8);
        nf0 = __builtin_nontemporal_load(s4);
        nf1 = __builtin_nontemporal_load(s4 + 1);
      }
    }

    // ---- phase 1: r for own 16 edges -> swizzled LDS ----------------------
    const int e_l = wv * 16 + erow;
    F8 fb; fb.i4 = make_int4(0, 0, 0, 0);
    if (kgrp < 2){
      fb.b[0]=(__bf16)f0.x; fb.b[1]=(__bf16)f0.y; fb.b[2]=(__bf16)f0.z; fb.b[3]=(__bf16)f0.w;
      fb.b[4]=(__bf16)f1.x; fb.b[5]=(__bf16)f1.y; fb.b[6]=(__bf16)f1.z; fb.b[7]=(__bf16)f1.w;
    }
    #pragma unroll
    for (int t = 0; t < 8; ++t){
      f32x4 acc = {0.f, 0.f, 0.f, 0.f};
      acc = __builtin_amdgcn_mfma_f32_16x16x32_bf16(wr[t].b, fb.b, acc, 0, 0, 0);
      B4 pk;
      pk.b4[0] = (__bf16)silu_f(acc[0] + bias[t].x);
      pk.b4[1] = (__bf16)silu_f(acc[1] + bias[t].y);
      pk.b4[2] = (__bf16)silu_f(acc[2] + bias[t].z);
      pk.b4[3] = (__bf16)silu_f(acc[3] + bias[t].w);
      int byte = (e_l << 8) + t * 32 + kgrp * 8;
      byte ^= (e_l & 7) << 4;
      *(int2*)(rb + byte) = pk.i2;
    }

    asm volatile("s_waitcnt lgkmcnt(0)" ::: "memory");
    __builtin_amdgcn_s_barrier();

    // ---- phase 2 + epilogue: own n-slice for all 128 edges ----------------
    const int nb = wv * 16 + kgrp * 4;
    #pragma unroll
    for (int eg = 0; eg < 8; ++eg){
      const int ed = eg * 16 + erow;
      f32x4 acc = {0.f, 0.f, 0.f, 0.f};
      #pragma unroll
      for (int s = 0; s < 4; ++s){
        int byte = (ed << 8) + s * 64 + kgrp * 16;
        byte ^= (ed & 7) << 4;
        F8 bB; bB.i4 = *(const int4*)(rb + byte);
        acc = __builtin_amdgcn_mfma_f32_16x16x32_bf16(w3[s].b, bB.b, acc, 0, 0, 0);
      }
      int a = aL[ed], b = bL[ed];
      f32x4 p1 = *(const f32x4*)(Pl + a * 260 + nb);
      f32x4 p2 = *(const f32x4*)(Pl + b * 260 + 128 + nb);
      f32x4 o;
      o.x = silu_f(acc[0] + p1.x + p2.x);
      o.y = silu_f(acc[1] + p1.y + p2.y);
      o.z = silu_f(acc[2] + p1.z + p2.z);
      o.w = silu_f(acc[3] + p1.w + p2.w);
      long ge = base + ed;
      if (ge < E)
        *(f32x4*)(out + ge * HID + nb) = o;
    }

    asm volatile("s_waitcnt lgkmcnt(0)" ::: "memory");
    __builtin_amdgcn_s_barrier();

    f0 = nf0; f1 = nf1;
    tile = next;
  }
}

// ---------------------------------------------------------------------------
extern "C" void kernel_launch(void* const* d_in, const int* in_sizes, int n_in,
                              void* d_out, int out_size, void* d_ws, size_t ws_size,
                              hipStream_t stream){
  const int*   x    = (const int*)  d_in[0];
  const float* rbf  = (const float*)d_in[1];
  const int*   ei   = (const int*)  d_in[2];
  const int*   ej   = (const int*)  d_in[3];
  const float* emb  = (const float*)d_in[4];
  const float* Wrbf = (const float*)d_in[5];
  const float* brbf = (const float*)d_in[6];
  const float* Wlin = (const float*)d_in[7];
  const float* blin = (const float*)d_in[8];
  float* out = (float*)d_out;

  const int E      = in_sizes[2];
  const int ntypes = in_sizes[4] / HID;   // 100

  float*          P     = (float*)d_ws;
  unsigned short* W3    = (unsigned short*)((char*)d_ws + (size_t)ntypes * 256 * sizeof(float));
  unsigned short* WrbfB = (unsigned short*)((char*)W3 + (size_t)HID * HID * sizeof(unsigned short));

  setup_kernel<<<ntypes + 64 + 8, 256, 0, stream>>>(emb, Wlin, blin, Wrbf, ntypes, P, W3, WrbfB);

  (void)hipFuncSetAttribute(reinterpret_cast<const void*>(&edge_kernel),
                            hipFuncAttributeMaxDynamicSharedMemorySize, LDS_BYTES);

  const int ntile = (E + 127) / 128;
  const int nblk  = ntile < 256 ? ntile : 256;
  edge_kernel<<<nblk, 512, LDS_BYTES, stream>>>(rbf, ei, ej, x, WrbfB, brbf, P, W3, out, E, ntile);
}